// Round 7
// baseline (231.263 us; speedup 1.0000x reference)
//
#include <hip/hip_runtime.h>
#include <hip/hip_bf16.h>
#include <stdint.h>
#include <math.h>

#define DI __device__ __forceinline__

typedef unsigned short u16;
typedef __bf16   bf16x8 __attribute__((ext_vector_type(8)));
typedef float    f32x4  __attribute__((ext_vector_type(4)));

// Problem constants
#define BSZ 4
#define SEQ 2048
#define DMODEL 1024
#define NHEAD 16
#define DHEAD 64

DI u16 f2b(float f) {            // fp32 -> bf16 bits, round-to-nearest-even
    uint32_t u = __float_as_uint(f);
    u += 0x7fffu + ((u >> 16) & 1u);
    return (u16)(u >> 16);
}

DI uint32_t f2b2(float a, float b) {   // packed cvt (v_cvt_pk_bf16_f32 on gfx950)
    __hip_bfloat162 h = __float22bfloat162_rn(float2{a, b});
    uint32_t u; __builtin_memcpy(&u, &h, 4); return u;
}

DI void async16(const void* g, void* l) {
    __builtin_amdgcn_global_load_lds(
        (const __attribute__((address_space(1))) void*)g,
        (__attribute__((address_space(3))) void*)l, 16, 0, 0);
}

// ---------------- fused cast kernel: fp32 -> bf16, all three arrays ---------
// x: 2097152 float4s, w_qkv: 786432, w_fc: 262144 -> 3145728 = 12288 * 256
__global__ __launch_bounds__(256) void cast_all(
    const float* __restrict__ x,  const float* __restrict__ wq,
    const float* __restrict__ wf, u16* __restrict__ xb,
    u16* __restrict__ wqb, u16* __restrict__ wfb)
{
    const int idx = blockIdx.x * 256 + threadIdx.x;
    const float* src; u16* dst; int off;
    if (idx < 2097152)      { src = x;  dst = xb;  off = idx; }
    else if (idx < 2883584) { src = wq; dst = wqb; off = idx - 2097152; }
    else                    { src = wf; dst = wfb; off = idx - 2883584; }
    const int i = off * 4;
    f32x4 v = *(const f32x4*)(src + i);
    *(uint2*)(dst + i) = make_uint2(f2b2(v[0], v[1]), f2b2(v[2], v[3]));
}

// ---------------- QKV GEMM (R5 control: scatter epilogue) -------------------
// C[M,N] = A[M,K] * B[N,K]^T, BK=64, XOR chunk swizzle (0 bank conflicts),
// epilogue scatters bf16 into q/k/v buffers laid out [B,H,S,64].
__global__ __launch_bounds__(256) void gemm_qkv(
    const u16* __restrict__ A, const u16* __restrict__ Bm, int K,
    u16* __restrict__ qb, u16* __restrict__ kb, u16* __restrict__ vb)
{
    __shared__ u16 As[128 * 64];
    __shared__ u16 Bs[128 * 64];

    const int tid  = threadIdx.x;
    const int l    = tid & 63, w = tid >> 6;
    const int quad = l >> 4, lc = l & 15;
    const int wm   = w >> 1, wn = w & 1;
    const int m0   = blockIdx.y * 128, n0 = blockIdx.x * 128;

    f32x4 acc[4][4];
#pragma unroll
    for (int i = 0; i < 4; i++)
#pragma unroll
        for (int j = 0; j < 4; j++) acc[i][j] = (f32x4){0.f, 0.f, 0.f, 0.f};

    const int  srow   = tid >> 3;
    const int  schunk = (tid & 7) ^ (srow & 7);
    const size_t aBase = (size_t)(m0 + srow) * K + schunk * 8;
    const size_t bBase = (size_t)(n0 + srow) * K + schunk * 8;

    for (int k0 = 0; k0 < K; k0 += 64) {
        __syncthreads();
#pragma unroll
        for (int i = 0; i < 4; i++) {
            async16(A  + aBase + (size_t)(32 * i) * K + k0, As + i * 2048 + w * 512);
            async16(Bm + bBase + (size_t)(32 * i) * K + k0, Bs + i * 2048 + w * 512);
        }
        __syncthreads();

#pragma unroll
        for (int kh = 0; kh < 2; kh++) {
            bf16x8 af[4], bf[4];
            const int g = kh * 4 + quad;
#pragma unroll
            for (int mi = 0; mi < 4; mi++) {
                const int mr = wm * 64 + mi * 16 + lc;
                af[mi] = *(const bf16x8*)&As[mr * 64 + ((g ^ (mr & 7)) * 8)];
            }
#pragma unroll
            for (int ni = 0; ni < 4; ni++) {
                const int nr = wn * 64 + ni * 16 + lc;
                bf[ni] = *(const bf16x8*)&Bs[nr * 64 + ((g ^ (nr & 7)) * 8)];
            }
#pragma unroll
            for (int mi = 0; mi < 4; mi++)
#pragma unroll
                for (int ni = 0; ni < 4; ni++)
                    acc[mi][ni] = __builtin_amdgcn_mfma_f32_16x16x32_bf16(
                        af[mi], bf[ni], acc[mi][ni], 0, 0, 0);
        }
    }

#pragma unroll
    for (int mi = 0; mi < 4; mi++) {
        const int mrow = m0 + wm * 64 + mi * 16 + quad * 4;
#pragma unroll
        for (int ni = 0; ni < 4; ni++) {
            const int e = n0 + wn * 64 + ni * 16 + lc;
#pragma unroll
            for (int r = 0; r < 4; r++) {
                const int m = mrow + r;
                const int part = e >> 10, rem = e & 1023;
                const int h = rem >> 6, dh = rem & 63;
                const int b = m >> 11, s = m & 2047;
                u16* dst = (part == 0) ? qb : ((part == 1) ? kb : vb);
                dst[(((size_t)(b * NHEAD + h) * SEQ + s) << 6) + dh] = f2b(acc[mi][ni][r]);
            }
        }
    }
}

// ---------------- out-proj GEMM: 64M x 128N tiles, dbuf LDS -----------------
// R6 lesson: splitting N duplicates A-strip HBM fetch (A is the big stream).
// Split M instead: A traffic unchanged (128 MB), only B duplicates (2 MB
// weight, L2-resident). Grid (8,128) = 1024 blocks; dbuf LDS 48 KB ->
// 3 blocks/CU. Epilogue: + bias, fp32 direct store.
__global__ __launch_bounds__(256) void gemm_fc(
    const u16* __restrict__ A, const u16* __restrict__ Bm, int K,
    const float* __restrict__ bias, float* __restrict__ outF, int N)
{
    __shared__ u16 As[2][64 * 64];
    __shared__ u16 Bs[2][128 * 64];

    const int tid  = threadIdx.x;
    const int l    = tid & 63, w = tid >> 6;
    const int quad = l >> 4, lc = l & 15;
    const int wm   = w >> 1, wn = w & 1;     // wave tile: 32M x 64N
    const int m0   = blockIdx.y * 64, n0 = blockIdx.x * 128;

    f32x4 acc[2][4];
#pragma unroll
    for (int i = 0; i < 2; i++)
#pragma unroll
        for (int j = 0; j < 4; j++) acc[i][j] = (f32x4){0.f, 0.f, 0.f, 0.f};

    const int  srow   = tid >> 3;
    const int  schunk = (tid & 7) ^ (srow & 7);
    const size_t aBase = (size_t)(m0 + srow) * K + schunk * 8;
    const size_t bBase = (size_t)(n0 + srow) * K + schunk * 8;

    const int NT = K / 64;   // 16 tiles

    // prologue: stage tile 0 into buf 0 (A: 2 issues, B: 4 issues per wave)
#pragma unroll
    for (int i = 0; i < 2; i++)
        async16(A + aBase + (size_t)(32 * i) * K, As[0] + i * 2048 + w * 512);
#pragma unroll
    for (int i = 0; i < 4; i++)
        async16(Bm + bBase + (size_t)(32 * i) * K, Bs[0] + i * 2048 + w * 512);
    __syncthreads();

    for (int kt = 0; kt < NT; ++kt) {
        const int cur = kt & 1;
        if (kt + 1 < NT) {
            const int nxt = (kt + 1) & 1;
            const int k0  = (kt + 1) * 64;
#pragma unroll
            for (int i = 0; i < 2; i++)
                async16(A + aBase + (size_t)(32 * i) * K + k0, As[nxt] + i * 2048 + w * 512);
#pragma unroll
            for (int i = 0; i < 4; i++)
                async16(Bm + bBase + (size_t)(32 * i) * K + k0, Bs[nxt] + i * 2048 + w * 512);
        }

#pragma unroll
        for (int kh = 0; kh < 2; kh++) {
            bf16x8 af[2], bf[4];
            const int g = kh * 4 + quad;
#pragma unroll
            for (int mi = 0; mi < 2; mi++) {
                const int mr = wm * 32 + mi * 16 + lc;
                af[mi] = *(const bf16x8*)&As[cur][mr * 64 + ((g ^ (mr & 7)) * 8)];
            }
#pragma unroll
            for (int ni = 0; ni < 4; ni++) {
                const int nr = wn * 64 + ni * 16 + lc;
                bf[ni] = *(const bf16x8*)&Bs[cur][nr * 64 + ((g ^ (nr & 7)) * 8)];
            }
#pragma unroll
            for (int mi = 0; mi < 2; mi++)
#pragma unroll
                for (int ni = 0; ni < 4; ni++)
                    acc[mi][ni] = __builtin_amdgcn_mfma_f32_16x16x32_bf16(
                        af[mi], bf[ni], acc[mi][ni], 0, 0, 0);
        }
        __syncthreads();   // drains prefetch; next iter consumes it
    }

#pragma unroll
    for (int mi = 0; mi < 2; mi++) {
        const int mrow = m0 + wm * 32 + mi * 16 + quad * 4;
#pragma unroll
        for (int ni = 0; ni < 4; ni++) {
            const int e = n0 + wn * 64 + ni * 16 + lc;
            const float be = bias[e];
#pragma unroll
            for (int r = 0; r < 4; r++)
                outF[(size_t)(mrow + r) * N + e] = acc[mi][ni][r] + be;
        }
    }
}

// ---------------- fused attention (flash-style, static-max softmax) ---------
// grid: (S/64, H, B); block 256 = 4 waves; wave w owns 16 q-rows (1 m-tile).
// 64-row q-blocks: 4+ blocks/CU (LDS 26.6 KB) and a tighter Gaussian window.
// Gaussian window: keys at distance d carry weight <= exp(gap - shift*d^2);
// cutoff shift*d^2 > 30 -> skipped mass < ~4e-6 (bf16 floor is ~0.03).
// Static-max softmax: p = exp(s - 8) exact in fp32 (scores bounded ~|s|<10).
#define PST 72   // Ps/Vt LDS row stride (u16): mult of 8 for b128, non-pow2 banks
__global__ __launch_bounds__(256) void attn_kernel(
    const u16* __restrict__ Q, const u16* __restrict__ Kg, const u16* __restrict__ Vg,
    const int* __restrict__ mask, const int* __restrict__ gaussp,
    const float* __restrict__ shiftp, const float* __restrict__ biaspp,
    u16* __restrict__ outA)
{
    __shared__ u16 Ks[8 * 64 * 8];     // [cb 0..7][row 0..63][8] (global_load_lds layout)
    __shared__ u16 Vt[64 * PST];       // transposed V: Vt[dh][k]
    __shared__ u16 Ps[64 * PST];       // P tiles, row = w*16 + local row (A-layout)

    const int tid  = threadIdx.x;
    const int l    = tid & 63, w = tid >> 6;
    const int quad = l >> 4, lc = l & 15;
    const int qt = blockIdx.x, h = blockIdx.y, b = blockIdx.z;
    const int bh = b * NHEAD + h;
    const int q0 = qt * 64;

    const float shift = shiftp[0];
    const float biasp = biaspp[0];
    const int   gauss = gaussp[0];

    const u16* Qbase = Q  + ((size_t)bh * SEQ << 6);
    const u16* Kbase = Kg + ((size_t)bh * SEQ << 6);
    const u16* Vbase = Vg + ((size_t)bh * SEQ << 6);
    const int* mbase = mask + b * SEQ;

    // Gaussian locality window (block-uniform)
    int kt_lo = 0, kt_hi = SEQ / 64 - 1;
    if (gauss) {
        const int dwin = (int)__fsqrt_rn(30.0f / shift) + 1;
        int lo = q0 - dwin;          if (lo < 0) lo = 0;
        int hi = q0 + 63 + dwin;     if (hi > SEQ - 1) hi = SEQ - 1;
        kt_lo = lo >> 6;
        kt_hi = hi >> 6;
    }

    // Q fragment: wave w rows q0 + w*16 + lc, d = ks*32 + quad*8
    bf16x8 qf[2];
#pragma unroll
    for (int ks = 0; ks < 2; ks++)
        qf[ks] = *(const bf16x8*)(Qbase +
            ((size_t)(q0 + w * 16 + lc) << 6) + ks * 32 + quad * 8);

    f32x4 oacc[4];
#pragma unroll
    for (int dt = 0; dt < 4; dt++) oacc[dt] = (f32x4){0.f, 0.f, 0.f, 0.f};
    float lsum[4];
#pragma unroll
    for (int r = 0; r < 4; r++) lsum[r] = 0.f;

    for (int kt = kt_lo; kt <= kt_hi; ++kt) {
        const int kk0 = kt * 64;
        __syncthreads();   // protect Ks/Vt reuse

        // stage K tile: issue0 cb=w, issue1 cb=4+w ; row = lane
        async16(Kbase + (size_t)(kk0 + l) * 64 + w * 8,       Ks + w * 512);
        async16(Kbase + (size_t)(kk0 + l) * 64 + (4 + w) * 8, Ks + 2048 + w * 512);

        // stage V transposed: wave w -> dh rows [w*16, w*16+16), lane = key index
        {
            const u16* vg = Vbase + (size_t)(kk0 + l) * 64 + w * 16;
            bf16x8 v0 = *(const bf16x8*)vg;
            bf16x8 v1 = *(const bf16x8*)(vg + 8);
            const u16* v0b = (const u16*)&v0;
            const u16* v1b = (const u16*)&v1;
#pragma unroll
            for (int j = 0; j < 8; j++) Vt[(w * 16 + j) * PST + l] = v0b[j];
#pragma unroll
            for (int j = 0; j < 8; j++) Vt[(w * 16 + 8 + j) * PST + l] = v1b[j];
        }
        __syncthreads();   // staging + transpose visible

        // ---- QK^T : S[q 16][kk 64] per wave ----
        bf16x8 kf[4][2];
#pragma unroll
        for (int nt = 0; nt < 4; nt++)
#pragma unroll
            for (int ks = 0; ks < 2; ks++)
                kf[nt][ks] = *(const bf16x8*)&Ks[(ks * 4 + quad) * 512 + (nt * 16 + lc) * 8];

        f32x4 sf[4];
#pragma unroll
        for (int nt = 0; nt < 4; nt++) sf[nt] = (f32x4){0.f, 0.f, 0.f, 0.f};
#pragma unroll
        for (int nt = 0; nt < 4; nt++)
#pragma unroll
            for (int ks = 0; ks < 2; ks++)
                sf[nt] = __builtin_amdgcn_mfma_f32_16x16x32_bf16(
                    qf[ks], kf[nt][ks], sf[nt], 0, 0, 0);

        // ---- mask + Gaussian + static-max softmax ----
        float madd[4]; float jj[4];
#pragma unroll
        for (int nt = 0; nt < 4; nt++) {
            const int j = kk0 + nt * 16 + lc;
            madd[nt] = mbase[j] ? 0.f : -1e30f;
            jj[nt] = (float)j;
        }
#pragma unroll
        for (int r = 0; r < 4; r++) {
            const float fi = (float)(q0 + w * 16 + quad * 4 + r);
            float p[4];
#pragma unroll
            for (int nt = 0; nt < 4; nt++) {
                float s = sf[nt][r] * 0.125f + madd[nt] - 8.0f;
                if (gauss) { const float d = fi - jj[nt]; s -= shift * d * d + biasp; }
                p[nt] = __expf(s);
            }
            lsum[r] += (p[0] + p[1]) + (p[2] + p[3]);
            const uint32_t p01 = f2b2(p[0], p[1]);
            const uint32_t p23 = f2b2(p[2], p[3]);
            u16* prow = &Ps[(w * 16 + quad * 4 + r) * PST + lc];
            prow[0]  = (u16)p01;  prow[16] = (u16)(p01 >> 16);
            prow[32] = (u16)p23;  prow[48] = (u16)(p23 >> 16);
        }

        // ---- P·V ----
        bf16x8 pa[2], vf[4][2];
#pragma unroll
        for (int ks = 0; ks < 2; ks++)
            pa[ks] = *(const bf16x8*)&Ps[(w * 16 + lc) * PST + ks * 32 + quad * 8];
#pragma unroll
        for (int dt = 0; dt < 4; dt++)
#pragma unroll
            for (int ks = 0; ks < 2; ks++)
                vf[dt][ks] = *(const bf16x8*)&Vt[(dt * 16 + lc) * PST + ks * 32 + quad * 8];
#pragma unroll
        for (int dt = 0; dt < 4; dt++)
#pragma unroll
            for (int ks = 0; ks < 2; ks++)
                oacc[dt] = __builtin_amdgcn_mfma_f32_16x16x32_bf16(
                    pa[ks], vf[dt][ks], oacc[dt], 0, 0, 0);
    }

    // row sums: reduce lsum across the 16 lc lanes (stays within quad group)
    float lrow[4];
#pragma unroll
    for (int r = 0; r < 4; r++) {
        float ts = lsum[r];
        ts += __shfl_xor(ts, 1);
        ts += __shfl_xor(ts, 2);
        ts += __shfl_xor(ts, 4);
        ts += __shfl_xor(ts, 8);
        lrow[r] = ts;
    }

    // epilogue: out[b, q, h*64+dh] = O / l   (bf16)
#pragma unroll
    for (int dt = 0; dt < 4; dt++)
#pragma unroll
        for (int r = 0; r < 4; r++) {
            const int qg  = q0 + w * 16 + quad * 4 + r;
            const int col = h * 64 + dt * 16 + lc;
            const float v = oacc[dt][r] / lrow[r];
            outA[((size_t)(b * SEQ + qg) << 10) + col] = f2b(v);
        }
}

// ---------------------------------------------------------------------------
extern "C" void kernel_launch(void* const* d_in, const int* in_sizes, int n_in,
                              void* d_out, int out_size, void* d_ws, size_t ws_size,
                              hipStream_t stream)
{
    const float* x      = (const float*)d_in[0];
    const int*   mask   = (const int*)d_in[1];
    // d_in[2] = qmask (unused by reference)
    const int*   gaussp = (const int*)d_in[3];
    const float* w_qkv  = (const float*)d_in[4];
    const float* w_fc   = (const float*)d_in[5];
    const float* b_fc   = (const float*)d_in[6];
    const float* shiftp = (const float*)d_in[7];
    const float* biaspp = (const float*)d_in[8];
    float* out = (float*)d_out;

    char* ws = (char*)d_ws;
    u16* xb  = (u16*)(ws);               // x bf16, later reused as attn_out (16.78 MB)
    u16* wqb = (u16*)(ws + 16777216);    // w_qkv bf16 (6.29 MB)
    u16* wfb = (u16*)(ws + 23068672);    // w_fc bf16 (2.10 MB)
    u16* qb  = (u16*)(ws + 25165824);    // Q bf16 [B,H,S,64] (16.78 MB)
    u16* kb  = (u16*)(ws + 41943040);    // K bf16 (16.78 MB)
    u16* vb  = (u16*)(ws + 58720256);    // V bf16 (16.78 MB) -> total 75.5 MB

    cast_all<<<12288, 256, 0, stream>>>(x, w_qkv, w_fc, xb, wqb, wfb);

    // QKV projection: M=8192, N=3072, K=1024
    gemm_qkv<<<dim3(24, 64), 256, 0, stream>>>(xb, wqb, DMODEL, qb, kb, vb);

    // fused attention -> attn_out (reuses xb)
    attn_kernel<<<dim3(SEQ / 64, NHEAD, BSZ), 256, 0, stream>>>(
        qb, kb, vb, mask, gaussp, shiftp, biaspp, xb);

    // output projection: M=8192, N=1024, K=1024, 64Mx128N tiles, dbuf, + bias
    gemm_fc<<<dim3(8, 128), 256, 0, stream>>>(xb, wfb, DMODEL, b_fc, out, DMODEL);
}

// Round 9
// 223.335 us; speedup vs baseline: 1.0355x; 1.0355x over previous
//
#include <hip/hip_runtime.h>
#include <hip/hip_bf16.h>
#include <stdint.h>
#include <math.h>

#define DI __device__ __forceinline__

typedef unsigned short u16;
typedef __bf16   bf16x8 __attribute__((ext_vector_type(8)));
typedef float    f32x4  __attribute__((ext_vector_type(4)));

// Problem constants
#define BSZ 4
#define SEQ 2048
#define DMODEL 1024
#define NHEAD 16
#define DHEAD 64

DI u16 f2b(float f) {            // fp32 -> bf16 bits, round-to-nearest-even
    uint32_t u = __float_as_uint(f);
    u += 0x7fffu + ((u >> 16) & 1u);
    return (u16)(u >> 16);
}

DI uint32_t f2b2(float a, float b) {   // packed cvt (v_cvt_pk_bf16_f32 on gfx950)
    __hip_bfloat162 h = __float22bfloat162_rn(float2{a, b});
    uint32_t u; __builtin_memcpy(&u, &h, 4); return u;
}

DI void async16(const void* g, void* l) {
    __builtin_amdgcn_global_load_lds(
        (const __attribute__((address_space(1))) void*)g,
        (__attribute__((address_space(3))) void*)l, 16, 0, 0);
}

// ---------------- fused cast kernel: fp32 -> bf16, all three arrays ---------
// x: 2097152 float4s, w_qkv: 786432, w_fc: 262144 -> 3145728 = 12288 * 256
__global__ __launch_bounds__(256) void cast_all(
    const float* __restrict__ x,  const float* __restrict__ wq,
    const float* __restrict__ wf, u16* __restrict__ xb,
    u16* __restrict__ wqb, u16* __restrict__ wfb)
{
    const int idx = blockIdx.x * 256 + threadIdx.x;
    const float* src; u16* dst; int off;
    if (idx < 2097152)      { src = x;  dst = xb;  off = idx; }
    else if (idx < 2883584) { src = wq; dst = wqb; off = idx - 2097152; }
    else                    { src = wf; dst = wfb; off = idx - 2883584; }
    const int i = off * 4;
    f32x4 v = *(const f32x4*)(src + i);
    *(uint2*)(dst + i) = make_uint2(f2b2(v[0], v[1]), f2b2(v[2], v[3]));
}

// ---------------- QKV GEMM (R5 control: scatter epilogue) -------------------
// C[M,N] = A[M,K] * B[N,K]^T, BK=64, XOR chunk swizzle (0 bank conflicts),
// epilogue scatters bf16 into q/k/v buffers laid out [B,H,S,64].
__global__ __launch_bounds__(256) void gemm_qkv(
    const u16* __restrict__ A, const u16* __restrict__ Bm, int K,
    u16* __restrict__ qb, u16* __restrict__ kb, u16* __restrict__ vb)
{
    __shared__ u16 As[128 * 64];
    __shared__ u16 Bs[128 * 64];

    const int tid  = threadIdx.x;
    const int l    = tid & 63, w = tid >> 6;
    const int quad = l >> 4, lc = l & 15;
    const int wm   = w >> 1, wn = w & 1;
    const int m0   = blockIdx.y * 128, n0 = blockIdx.x * 128;

    f32x4 acc[4][4];
#pragma unroll
    for (int i = 0; i < 4; i++)
#pragma unroll
        for (int j = 0; j < 4; j++) acc[i][j] = (f32x4){0.f, 0.f, 0.f, 0.f};

    const int  srow   = tid >> 3;
    const int  schunk = (tid & 7) ^ (srow & 7);
    const size_t aBase = (size_t)(m0 + srow) * K + schunk * 8;
    const size_t bBase = (size_t)(n0 + srow) * K + schunk * 8;

    for (int k0 = 0; k0 < K; k0 += 64) {
        __syncthreads();
#pragma unroll
        for (int i = 0; i < 4; i++) {
            async16(A  + aBase + (size_t)(32 * i) * K + k0, As + i * 2048 + w * 512);
            async16(Bm + bBase + (size_t)(32 * i) * K + k0, Bs + i * 2048 + w * 512);
        }
        __syncthreads();

#pragma unroll
        for (int kh = 0; kh < 2; kh++) {
            bf16x8 af[4], bf[4];
            const int g = kh * 4 + quad;
#pragma unroll
            for (int mi = 0; mi < 4; mi++) {
                const int mr = wm * 64 + mi * 16 + lc;
                af[mi] = *(const bf16x8*)&As[mr * 64 + ((g ^ (mr & 7)) * 8)];
            }
#pragma unroll
            for (int ni = 0; ni < 4; ni++) {
                const int nr = wn * 64 + ni * 16 + lc;
                bf[ni] = *(const bf16x8*)&Bs[nr * 64 + ((g ^ (nr & 7)) * 8)];
            }
#pragma unroll
            for (int mi = 0; mi < 4; mi++)
#pragma unroll
                for (int ni = 0; ni < 4; ni++)
                    acc[mi][ni] = __builtin_amdgcn_mfma_f32_16x16x32_bf16(
                        af[mi], bf[ni], acc[mi][ni], 0, 0, 0);
        }
    }

#pragma unroll
    for (int mi = 0; mi < 4; mi++) {
        const int mrow = m0 + wm * 64 + mi * 16 + quad * 4;
#pragma unroll
        for (int ni = 0; ni < 4; ni++) {
            const int e = n0 + wn * 64 + ni * 16 + lc;
#pragma unroll
            for (int r = 0; r < 4; r++) {
                const int m = mrow + r;
                const int part = e >> 10, rem = e & 1023;
                const int h = rem >> 6, dh = rem & 63;
                const int b = m >> 11, s = m & 2047;
                u16* dst = (part == 0) ? qb : ((part == 1) ? kb : vb);
                dst[(((size_t)(b * NHEAD + h) * SEQ + s) << 6) + dh] = f2b(acc[mi][ni][r]);
            }
        }
    }
}

// ---------------- out-proj GEMM (R5 config: 128x128, dbuf, 2 blocks/CU) -----
// R6/R7 lesson: both N-split and M-split tilings lose more per-block compute
// density than they gain in latency coverage. 128x128 dbuf is the best
// measured config. Epilogue: + bias, fp32 direct store.
__global__ __launch_bounds__(256) void gemm_fc(
    const u16* __restrict__ A, const u16* __restrict__ Bm, int K,
    const float* __restrict__ bias, float* __restrict__ outF, int N)
{
    __shared__ u16 As[2][128 * 64];
    __shared__ u16 Bs[2][128 * 64];

    const int tid  = threadIdx.x;
    const int l    = tid & 63, w = tid >> 6;
    const int quad = l >> 4, lc = l & 15;
    const int wm   = w >> 1, wn = w & 1;
    const int m0   = blockIdx.y * 128, n0 = blockIdx.x * 128;

    f32x4 acc[4][4];
#pragma unroll
    for (int i = 0; i < 4; i++)
#pragma unroll
        for (int j = 0; j < 4; j++) acc[i][j] = (f32x4){0.f, 0.f, 0.f, 0.f};

    const int  srow   = tid >> 3;
    const int  schunk = (tid & 7) ^ (srow & 7);
    const size_t aBase = (size_t)(m0 + srow) * K + schunk * 8;
    const size_t bBase = (size_t)(n0 + srow) * K + schunk * 8;

    const int NT = K / 64;   // 16 tiles

#pragma unroll
    for (int i = 0; i < 4; i++) {
        async16(A  + aBase + (size_t)(32 * i) * K, As[0] + i * 2048 + w * 512);
        async16(Bm + bBase + (size_t)(32 * i) * K, Bs[0] + i * 2048 + w * 512);
    }
    __syncthreads();

    for (int kt = 0; kt < NT; ++kt) {
        const int cur = kt & 1;
        if (kt + 1 < NT) {
            const int nxt = (kt + 1) & 1;
            const int k0  = (kt + 1) * 64;
#pragma unroll
            for (int i = 0; i < 4; i++) {
                async16(A  + aBase + (size_t)(32 * i) * K + k0, As[nxt] + i * 2048 + w * 512);
                async16(Bm + bBase + (size_t)(32 * i) * K + k0, Bs[nxt] + i * 2048 + w * 512);
            }
        }

#pragma unroll
        for (int kh = 0; kh < 2; kh++) {
            bf16x8 af[4], bf[4];
            const int g = kh * 4 + quad;
#pragma unroll
            for (int mi = 0; mi < 4; mi++) {
                const int mr = wm * 64 + mi * 16 + lc;
                af[mi] = *(const bf16x8*)&As[cur][mr * 64 + ((g ^ (mr & 7)) * 8)];
            }
#pragma unroll
            for (int ni = 0; ni < 4; ni++) {
                const int nr = wn * 64 + ni * 16 + lc;
                bf[ni] = *(const bf16x8*)&Bs[cur][nr * 64 + ((g ^ (nr & 7)) * 8)];
            }
#pragma unroll
            for (int mi = 0; mi < 4; mi++)
#pragma unroll
                for (int ni = 0; ni < 4; ni++)
                    acc[mi][ni] = __builtin_amdgcn_mfma_f32_16x16x32_bf16(
                        af[mi], bf[ni], acc[mi][ni], 0, 0, 0);
        }
        __syncthreads();   // drains prefetch; next iter consumes it
    }

#pragma unroll
    for (int mi = 0; mi < 4; mi++) {
        const int mrow = m0 + wm * 64 + mi * 16 + quad * 4;
#pragma unroll
        for (int ni = 0; ni < 4; ni++) {
            const int e = n0 + wn * 64 + ni * 16 + lc;
            const float be = bias[e];
#pragma unroll
            for (int r = 0; r < 4; r++)
                outF[(size_t)(mrow + r) * N + e] = acc[mi][ni][r] + be;
        }
    }
}

// ---------------- fused attention: K/V double-buffer, 1 barrier/tile --------
// grid: (S/64, H, B); block 256 = 4 waves; wave w owns 16 q-rows (1 m-tile).
// Dbuf: stage K(t+1) via async16 + load V(t+1) to VGPRs BEFORE compute(t);
// V transpose-writes to the other buffer AFTER compute; one __syncthreads
// per tile (its vmcnt(0)+lgkmcnt(0) drain covers async16 + Vt writes).
// R8 bug fixed: one K tile = 64x64 bf16 = 4096 u16 per buffer (was
// mis-sized 2048 -> buffer overflow -> absmax 2.96).
// LDS ~43.6 KB -> 3 blocks/CU. Gaussian window: cutoff shift*d^2 > 30.
// Static-max softmax: p = exp(s - 8) exact in fp32 (scores bounded ~|s|<10).
#define PST 72   // Ps/Vt LDS row stride (u16): mult of 8 for b128, non-pow2 banks
__global__ __launch_bounds__(256) void attn_kernel(
    const u16* __restrict__ Q, const u16* __restrict__ Kg, const u16* __restrict__ Vg,
    const int* __restrict__ mask, const int* __restrict__ gaussp,
    const float* __restrict__ shiftp, const float* __restrict__ biaspp,
    u16* __restrict__ outA)
{
    __shared__ u16 Ks[2][4096];        // [buf][cb 0..7][row 0..63][8] = 64x64 bf16/buf
    __shared__ u16 Vt[2][64 * PST];    // transposed V per buf
    __shared__ u16 Ps[64 * PST];       // P tiles, per-wave private rows

    const int tid  = threadIdx.x;
    const int l    = tid & 63, w = tid >> 6;
    const int quad = l >> 4, lc = l & 15;
    const int qt = blockIdx.x, h = blockIdx.y, b = blockIdx.z;
    const int bh = b * NHEAD + h;
    const int q0 = qt * 64;

    const float shift = shiftp[0];
    const float biasp = biaspp[0];
    const int   gauss = gaussp[0];

    const u16* Qbase = Q  + ((size_t)bh * SEQ << 6);
    const u16* Kbase = Kg + ((size_t)bh * SEQ << 6);
    const u16* Vbase = Vg + ((size_t)bh * SEQ << 6);
    const int* mbase = mask + b * SEQ;

    // Gaussian locality window (block-uniform)
    int kt_lo = 0, kt_hi = SEQ / 64 - 1;
    if (gauss) {
        const int dwin = (int)__fsqrt_rn(30.0f / shift) + 1;
        int lo = q0 - dwin;          if (lo < 0) lo = 0;
        int hi = q0 + 63 + dwin;     if (hi > SEQ - 1) hi = SEQ - 1;
        kt_lo = lo >> 6;
        kt_hi = hi >> 6;
    }

    // Q fragment: wave w rows q0 + w*16 + lc, d = ks*32 + quad*8
    bf16x8 qf[2];
#pragma unroll
    for (int ks = 0; ks < 2; ks++)
        qf[ks] = *(const bf16x8*)(Qbase +
            ((size_t)(q0 + w * 16 + lc) << 6) + ks * 32 + quad * 8);

    f32x4 oacc[4];
#pragma unroll
    for (int dt = 0; dt < 4; dt++) oacc[dt] = (f32x4){0.f, 0.f, 0.f, 0.f};
    float lsum[4];
#pragma unroll
    for (int r = 0; r < 4; r++) lsum[r] = 0.f;

    // ---- prologue: stage tile kt_lo into buffer 0 ----
    {
        const int kk0 = kt_lo * 64;
        async16(Kbase + (size_t)(kk0 + l) * 64 + w * 8,       Ks[0] + w * 512);
        async16(Kbase + (size_t)(kk0 + l) * 64 + (4 + w) * 8, Ks[0] + 2048 + w * 512);
        const u16* vg = Vbase + (size_t)(kk0 + l) * 64 + w * 16;
        bf16x8 v0 = *(const bf16x8*)vg;
        bf16x8 v1 = *(const bf16x8*)(vg + 8);
        const u16* v0b = (const u16*)&v0;
        const u16* v1b = (const u16*)&v1;
#pragma unroll
        for (int j = 0; j < 8; j++) Vt[0][(w * 16 + j) * PST + l] = v0b[j];
#pragma unroll
        for (int j = 0; j < 8; j++) Vt[0][(w * 16 + 8 + j) * PST + l] = v1b[j];
    }
    __syncthreads();

    for (int kt = kt_lo; kt <= kt_hi; ++kt) {
        const int cur = (kt - kt_lo) & 1;
        const int nxt = cur ^ 1;
        const bool pre = (kt < kt_hi);

        // ---- issue next tile's staging (K -> LDS DMA, V -> VGPRs) ----
        bf16x8 v0, v1;
        if (pre) {
            const int kk1 = (kt + 1) * 64;
            async16(Kbase + (size_t)(kk1 + l) * 64 + w * 8,       Ks[nxt] + w * 512);
            async16(Kbase + (size_t)(kk1 + l) * 64 + (4 + w) * 8, Ks[nxt] + 2048 + w * 512);
            const u16* vg = Vbase + (size_t)(kk1 + l) * 64 + w * 16;
            v0 = *(const bf16x8*)vg;
            v1 = *(const bf16x8*)(vg + 8);
        }

        const int kk0 = kt * 64;

        // ---- QK^T : S[q 16][kk 64] per wave ----
        bf16x8 kf[4][2];
#pragma unroll
        for (int nt = 0; nt < 4; nt++)
#pragma unroll
            for (int ks = 0; ks < 2; ks++)
                kf[nt][ks] = *(const bf16x8*)&Ks[cur][(ks * 4 + quad) * 512 + (nt * 16 + lc) * 8];

        f32x4 sf[4];
#pragma unroll
        for (int nt = 0; nt < 4; nt++) sf[nt] = (f32x4){0.f, 0.f, 0.f, 0.f};
#pragma unroll
        for (int nt = 0; nt < 4; nt++)
#pragma unroll
            for (int ks = 0; ks < 2; ks++)
                sf[nt] = __builtin_amdgcn_mfma_f32_16x16x32_bf16(
                    qf[ks], kf[nt][ks], sf[nt], 0, 0, 0);

        // ---- mask + Gaussian + static-max softmax ----
        float madd[4]; float jj[4];
#pragma unroll
        for (int nt = 0; nt < 4; nt++) {
            const int j = kk0 + nt * 16 + lc;
            madd[nt] = mbase[j] ? 0.f : -1e30f;
            jj[nt] = (float)j;
        }
#pragma unroll
        for (int r = 0; r < 4; r++) {
            const float fi = (float)(q0 + w * 16 + quad * 4 + r);
            float p[4];
#pragma unroll
            for (int nt = 0; nt < 4; nt++) {
                float s = sf[nt][r] * 0.125f + madd[nt] - 8.0f;
                if (gauss) { const float d = fi - jj[nt]; s -= shift * d * d + biasp; }
                p[nt] = __expf(s);
            }
            lsum[r] += (p[0] + p[1]) + (p[2] + p[3]);
            const uint32_t p01 = f2b2(p[0], p[1]);
            const uint32_t p23 = f2b2(p[2], p[3]);
            u16* prow = &Ps[(w * 16 + quad * 4 + r) * PST + lc];
            prow[0]  = (u16)p01;  prow[16] = (u16)(p01 >> 16);
            prow[32] = (u16)p23;  prow[48] = (u16)(p23 >> 16);
        }

        // ---- P·V ----
        bf16x8 pa[2], vf[4][2];
#pragma unroll
        for (int ks = 0; ks < 2; ks++)
            pa[ks] = *(const bf16x8*)&Ps[(w * 16 + lc) * PST + ks * 32 + quad * 8];
#pragma unroll
        for (int dt = 0; dt < 4; dt++)
#pragma unroll
            for (int ks = 0; ks < 2; ks++)
                vf[dt][ks] = *(const bf16x8*)&Vt[cur][(dt * 16 + lc) * PST + ks * 32 + quad * 8];
#pragma unroll
        for (int dt = 0; dt < 4; dt++)
#pragma unroll
            for (int ks = 0; ks < 2; ks++)
                oacc[dt] = __builtin_amdgcn_mfma_f32_16x16x32_bf16(
                    pa[ks], vf[dt][ks], oacc[dt], 0, 0, 0);

        // ---- write next V tile (transposed) into the other buffer ----
        if (pre) {
            const u16* v0b = (const u16*)&v0;
            const u16* v1b = (const u16*)&v1;
#pragma unroll
            for (int j = 0; j < 8; j++) Vt[nxt][(w * 16 + j) * PST + l] = v0b[j];
#pragma unroll
            for (int j = 0; j < 8; j++) Vt[nxt][(w * 16 + 8 + j) * PST + l] = v1b[j];
        }
        __syncthreads();   // drains async16 + V writes; next iter reads nxt
    }

    // row sums: reduce lsum across the 16 lc lanes (stays within quad group)
    float lrow[4];
#pragma unroll
    for (int r = 0; r < 4; r++) {
        float ts = lsum[r];
        ts += __shfl_xor(ts, 1);
        ts += __shfl_xor(ts, 2);
        ts += __shfl_xor(ts, 4);
        ts += __shfl_xor(ts, 8);
        lrow[r] = ts;
    }

    // epilogue: out[b, q, h*64+dh] = O / l   (bf16)
#pragma unroll
    for (int dt = 0; dt < 4; dt++)
#pragma unroll
        for (int r = 0; r < 4; r++) {
            const int qg  = q0 + w * 16 + quad * 4 + r;
            const int col = h * 64 + dt * 16 + lc;
            const float v = oacc[dt][r] / lrow[r];
            outA[((size_t)(b * SEQ + qg) << 10) + col] = f2b(v);
        }
}

// ---------------------------------------------------------------------------
extern "C" void kernel_launch(void* const* d_in, const int* in_sizes, int n_in,
                              void* d_out, int out_size, void* d_ws, size_t ws_size,
                              hipStream_t stream)
{
    const float* x      = (const float*)d_in[0];
    const int*   mask   = (const int*)d_in[1];
    // d_in[2] = qmask (unused by reference)
    const int*   gaussp = (const int*)d_in[3];
    const float* w_qkv  = (const float*)d_in[4];
    const float* w_fc   = (const float*)d_in[5];
    const float* b_fc   = (const float*)d_in[6];
    const float* shiftp = (const float*)d_in[7];
    const float* biaspp = (const float*)d_in[8];
    float* out = (float*)d_out;

    char* ws = (char*)d_ws;
    u16* xb  = (u16*)(ws);               // x bf16, later reused as attn_out (16.78 MB)
    u16* wqb = (u16*)(ws + 16777216);    // w_qkv bf16 (6.29 MB)
    u16* wfb = (u16*)(ws + 23068672);    // w_fc bf16 (2.10 MB)
    u16* qb  = (u16*)(ws + 25165824);    // Q bf16 [B,H,S,64] (16.78 MB)
    u16* kb  = (u16*)(ws + 41943040);    // K bf16 (16.78 MB)
    u16* vb  = (u16*)(ws + 58720256);    // V bf16 (16.78 MB) -> total 75.5 MB

    cast_all<<<12288, 256, 0, stream>>>(x, w_qkv, w_fc, xb, wqb, wfb);

    // QKV projection: M=8192, N=3072, K=1024
    gemm_qkv<<<dim3(24, 64), 256, 0, stream>>>(xb, wqb, DMODEL, qb, kb, vb);

    // fused attention -> attn_out (reuses xb)
    attn_kernel<<<dim3(SEQ / 64, NHEAD, BSZ), 256, 0, stream>>>(
        qb, kb, vb, mask, gaussp, shiftp, biaspp, xb);

    // output projection: M=8192, N=1024, K=1024, 128x128 dbuf, + bias
    gemm_fc<<<dim3(8, 64), 256, 0, stream>>>(xb, wfb, DMODEL, b_fc, out, DMODEL);
}